// Round 1
// baseline (425.602 us; speedup 1.0000x reference)
//
#include <hip/hip_runtime.h>

typedef unsigned int   u32;
typedef unsigned short u16;
typedef __bf16 bf16x8 __attribute__((ext_vector_type(8)));
typedef float  f32x4  __attribute__((ext_vector_type(4)));

__device__ __forceinline__ u16 f2bf(float f) {
    u32 u = __builtin_bit_cast(u32, f);
    u += 0x7FFFu + ((u >> 16) & 1u);
    return (u16)(u >> 16);
}

__device__ __forceinline__ bf16x8 ldfrag(const u16* p) {
    return __builtin_bit_cast(bf16x8, *reinterpret_cast<const uint4*>(p));
}

// ---------------------------------------------------------------------------
// Fused Swin branch: LN -> QKV -> windowed MHA -> proj -> +residual
// One workgroup per 8x8 window (64 tokens). 384 threads = 6 waves = 6 heads.
// ---------------------------------------------------------------------------
template<int SHIFT>
__global__ __launch_bounds__(384) void swin_branch(
    const float* __restrict__ xin, float* __restrict__ xout,
    const float* __restrict__ ln_g, const float* __restrict__ ln_b,
    const u16*   __restrict__ wqkv_t,  // [576][192] bf16 (pre-transposed)
    const float* __restrict__ qkv_b,   // [576]
    const u16*   __restrict__ wproj_t, // [192][192] bf16 (pre-transposed)
    const float* __restrict__ proj_b)  // [192]
{
    // y_ln [64][200] bf16; later reused as attn_out [64][200]
    __shared__ __align__(16) u16 yln[64*200];
    // per head: q[64][40] @0, k[64][40] @2560 ; P[64][72] overlays q+k (wave-local)
    __shared__ __align__(16) u16 hb[6][5120];
    // V transposed per head: [32 d][72 stride] tokens
    __shared__ __align__(16) u16 vt[6][2304];
    __shared__ float red1[6][64];
    __shared__ float red2[6][64];
    __shared__ float mu_s[64], rs_s[64];

    const int tid  = threadIdx.x;
    const int wid  = tid >> 6;      // wave / head
    const int lane = tid & 63;
    const int lr   = lane & 15;
    const int lg   = lane >> 4;

    const int Wid = blockIdx.x;     // window id: b*256 + wy*16 + wx
    const int b   = Wid >> 8;
    const int wy  = (Wid >> 4) & 15;
    const int wx  = Wid & 15;

    // ---- Phase 1: gather window (rolled coords), LayerNorm -> yln (bf16) ----
    {
        const int ty = lane >> 3, tx = lane & 7;
        const int sh = (wy*8 + ty + SHIFT) & 127;
        const int sw = (wx*8 + tx + SHIFT) & 127;
        const float* xp = xin + ((size_t)((b*128 + sh)*128 + sw))*192 + wid*32;
        float xv[32];
        float s1 = 0.f, s2 = 0.f;
        #pragma unroll
        for (int j = 0; j < 8; ++j) {
            float4 v = reinterpret_cast<const float4*>(xp)[j];
            xv[j*4+0]=v.x; xv[j*4+1]=v.y; xv[j*4+2]=v.z; xv[j*4+3]=v.w;
            s1 += v.x+v.y+v.z+v.w;
            s2 += v.x*v.x + v.y*v.y + v.z*v.z + v.w*v.w;
        }
        red1[wid][lane] = s1; red2[wid][lane] = s2;
        __syncthreads();
        if (tid < 64) {
            float a1 = 0.f, a2 = 0.f;
            #pragma unroll
            for (int w = 0; w < 6; ++w) { a1 += red1[w][tid]; a2 += red2[w][tid]; }
            float mu  = a1 * (1.f/192.f);
            float var = a2 * (1.f/192.f) - mu*mu;
            mu_s[tid] = mu;
            rs_s[tid] = rsqrtf(var + 1e-5f);
        }
        __syncthreads();
        const float mu = mu_s[lane], rs = rs_s[lane];
        const float* gp = ln_g + wid*32;
        const float* bp = ln_b + wid*32;
        u16* yrow = &yln[lane*200 + wid*32];
        #pragma unroll
        for (int j8 = 0; j8 < 4; ++j8) {
            u32 pk[4];
            #pragma unroll
            for (int q = 0; q < 4; ++q) {
                int j = j8*8 + q*2;
                float y0 = (xv[j]   - mu)*rs*gp[j]   + bp[j];
                float y1 = (xv[j+1] - mu)*rs*gp[j+1] + bp[j+1];
                pk[q] = (u32)f2bf(y0) | ((u32)f2bf(y1) << 16);
            }
            *reinterpret_cast<uint4*>(yrow + j8*8) = make_uint4(pk[0],pk[1],pk[2],pk[3]);
        }
    }
    __syncthreads();

    // ---- Phase 2: QKV GEMM  [64x192] @ [192x576], wave wid owns 96 out cols ----
    {
        const int nb = wid*96;
        f32x4 acc[4][6];
        #pragma unroll
        for (int mi=0; mi<4; ++mi)
            #pragma unroll
            for (int ni=0; ni<6; ++ni) acc[mi][ni] = f32x4{0.f,0.f,0.f,0.f};
        #pragma unroll
        for (int ks=0; ks<6; ++ks) {
            bf16x8 af[4];
            #pragma unroll
            for (int mi=0; mi<4; ++mi)
                af[mi] = ldfrag(&yln[(16*mi+lr)*200 + 32*ks + 8*lg]);
            bf16x8 bw[6];
            #pragma unroll
            for (int ni=0; ni<6; ++ni)
                bw[ni] = ldfrag(&wqkv_t[(nb + 16*ni + lr)*192 + 32*ks + 8*lg]);
            #pragma unroll
            for (int mi=0; mi<4; ++mi)
                #pragma unroll
                for (int ni=0; ni<6; ++ni)
                    acc[mi][ni] = __builtin_amdgcn_mfma_f32_16x16x32_bf16(af[mi], bw[ni], acc[mi][ni], 0,0,0);
        }
        // scatter q (scaled), k, v^T into LDS
        #pragma unroll
        for (int ni=0; ni<6; ++ni) {
            const int o   = nb + 16*ni + lr;
            const float bias = qkv_b[o];
            const int sec = o / 192;          // wave-uniform: 0=q 1=k 2=v
            const int oo  = o - sec*192;
            const int hh  = oo >> 5;
            const int dd  = oo & 31;
            #pragma unroll
            for (int mi=0; mi<4; ++mi)
                #pragma unroll
                for (int rg=0; rg<4; ++rg) {
                    const int row = 16*mi + 4*lg + rg;
                    float v = acc[mi][ni][rg] + bias;
                    if (sec == 0)      hb[hh][row*40 + dd] = f2bf(v * 0.1767766952966369f); // q/sqrt(32)
                    else if (sec == 1) hb[hh][2560 + row*40 + dd] = f2bf(v);
                    else               vt[hh][dd*72 + row] = f2bf(v);
                }
        }
    }
    __syncthreads();

    // ---- Phase 3: attention (wave-local, head hh = wid) ----
    float rsum[4][4];
    f32x4 o_[4][2];
    {
        const u16* qh = &hb[wid][0];
        const u16* kh = &hb[wid][2560];
        f32x4 s[4][4];
        #pragma unroll
        for (int mi=0; mi<4; ++mi)
            #pragma unroll
            for (int ni=0; ni<4; ++ni) s[mi][ni] = f32x4{0.f,0.f,0.f,0.f};

        bf16x8 aq[4], bk[4];
        #pragma unroll
        for (int mi=0; mi<4; ++mi) aq[mi] = ldfrag(&qh[(16*mi+lr)*40 + 8*lg]);
        #pragma unroll
        for (int ni=0; ni<4; ++ni) bk[ni] = ldfrag(&kh[(16*ni+lr)*40 + 8*lg]);
        #pragma unroll
        for (int mi=0; mi<4; ++mi)
            #pragma unroll
            for (int ni=0; ni<4; ++ni)
                s[mi][ni] = __builtin_amdgcn_mfma_f32_16x16x32_bf16(aq[mi], bk[ni], s[mi][ni], 0,0,0);

        if constexpr (SHIFT > 0) {
            int kl[4];
            #pragma unroll
            for (int ni=0; ni<4; ++ni) {
                const int col = 16*ni + lr;
                const int hu = wy*8 + (col>>3);
                const int wu = wx*8 + (col&7);
                const int ah = (hu >= 124) ? 2 : (hu >= 120 ? 1 : 0);
                const int aw = (wu >= 124) ? 2 : (wu >= 120 ? 1 : 0);
                kl[ni] = ah*3 + aw;
            }
            #pragma unroll
            for (int mi=0; mi<4; ++mi)
                #pragma unroll
                for (int rg=0; rg<4; ++rg) {
                    const int row = 16*mi + 4*lg + rg;
                    const int hu = wy*8 + (row>>3);
                    const int wu = wx*8 + (row&7);
                    const int ah = (hu >= 124) ? 2 : (hu >= 120 ? 1 : 0);
                    const int aw = (wu >= 124) ? 2 : (wu >= 120 ? 1 : 0);
                    const int rl = ah*3 + aw;
                    #pragma unroll
                    for (int ni=0; ni<4; ++ni)
                        if (rl != kl[ni]) s[mi][ni][rg] += -100.f;
                }
        }

        // row softmax in registers (row = 16*mi + 4*lg + rg, cols across 16 lanes x 4 ni)
        #pragma unroll
        for (int mi=0; mi<4; ++mi)
            #pragma unroll
            for (int rg=0; rg<4; ++rg) {
                float m = fmaxf(fmaxf(s[mi][0][rg], s[mi][1][rg]), fmaxf(s[mi][2][rg], s[mi][3][rg]));
                #pragma unroll
                for (int off=1; off<16; off<<=1) m = fmaxf(m, __shfl_xor(m, off, 64));
                float sm = 0.f;
                #pragma unroll
                for (int ni=0; ni<4; ++ni) {
                    float e = __expf(s[mi][ni][rg] - m);
                    s[mi][ni][rg] = e;
                    sm += e;
                }
                #pragma unroll
                for (int off=1; off<16; off<<=1) sm += __shfl_xor(sm, off, 64);
                rsum[mi][rg] = 1.0f / sm;
            }

        // write unnormalized P (bf16) over this head's q/k region — wave-local
        u16* ph = &hb[wid][0];
        #pragma unroll
        for (int mi=0; mi<4; ++mi)
            #pragma unroll
            for (int ni=0; ni<4; ++ni)
                #pragma unroll
                for (int rg=0; rg<4; ++rg)
                    ph[(16*mi + 4*lg + rg)*72 + 16*ni + lr] = f2bf(s[mi][ni][rg]);

        // PV: out[64][32] = P[64][64] @ V[64][32]
        #pragma unroll
        for (int mi=0; mi<4; ++mi)
            #pragma unroll
            for (int ni=0; ni<2; ++ni) o_[mi][ni] = f32x4{0.f,0.f,0.f,0.f};
        #pragma unroll
        for (int ks=0; ks<2; ++ks) {
            bf16x8 ap[4], bv[2];
            #pragma unroll
            for (int mi=0; mi<4; ++mi) ap[mi] = ldfrag(&ph[(16*mi+lr)*72 + 32*ks + 8*lg]);
            #pragma unroll
            for (int ni=0; ni<2; ++ni) bv[ni] = ldfrag(&vt[wid][(16*ni+lr)*72 + 32*ks + 8*lg]);
            #pragma unroll
            for (int mi=0; mi<4; ++mi)
                #pragma unroll
                for (int ni=0; ni<2; ++ni)
                    o_[mi][ni] = __builtin_amdgcn_mfma_f32_16x16x32_bf16(ap[mi], bv[ni], o_[mi][ni], 0,0,0);
        }
        // normalized attn output -> yln region (cols hh*32 + ...)
        #pragma unroll
        for (int mi=0; mi<4; ++mi)
            #pragma unroll
            for (int ni=0; ni<2; ++ni)
                #pragma unroll
                for (int rg=0; rg<4; ++rg) {
                    const int row = 16*mi + 4*lg + rg;
                    const int col = wid*32 + 16*ni + lr;
                    yln[row*200 + col] = f2bf(o_[mi][ni][rg] * rsum[mi][rg]);
                }
    }
    __syncthreads();

    // ---- Phase 4: proj GEMM [64x192] @ [192x192] + bias + residual ----
    {
        f32x4 a2[4][2];
        #pragma unroll
        for (int mi=0; mi<4; ++mi)
            #pragma unroll
            for (int ni=0; ni<2; ++ni) a2[mi][ni] = f32x4{0.f,0.f,0.f,0.f};
        #pragma unroll
        for (int ks=0; ks<6; ++ks) {
            bf16x8 af[4], bw[2];
            #pragma unroll
            for (int mi=0; mi<4; ++mi)
                af[mi] = ldfrag(&yln[(16*mi+lr)*200 + 32*ks + 8*lg]);
            #pragma unroll
            for (int ni=0; ni<2; ++ni)
                bw[ni] = ldfrag(&wproj_t[(wid*32 + 16*ni + lr)*192 + 32*ks + 8*lg]);
            #pragma unroll
            for (int mi=0; mi<4; ++mi)
                #pragma unroll
                for (int ni=0; ni<2; ++ni)
                    a2[mi][ni] = __builtin_amdgcn_mfma_f32_16x16x32_bf16(af[mi], bw[ni], a2[mi][ni], 0,0,0);
        }
        #pragma unroll
        for (int ni=0; ni<2; ++ni) {
            const int c  = wid*32 + 16*ni + lr;
            const float pb = proj_b[c];
            #pragma unroll
            for (int mi=0; mi<4; ++mi)
                #pragma unroll
                for (int rg=0; rg<4; ++rg) {
                    const int row = 16*mi + 4*lg + rg;
                    const int ty = row >> 3, tx = row & 7;
                    const int sh = (wy*8 + ty + SHIFT) & 127;
                    const int sw = (wx*8 + tx + SHIFT) & 127;
                    const size_t idx = ((size_t)((b*128 + sh)*128 + sw))*192 + c;
                    xout[idx] = xin[idx] + a2[mi][ni][rg] + pb;
                }
        }
    }
}

// Convert + transpose weights to bf16 once per call: ws layout (u16 units):
// [0) wqkv1_t 110592 | 110592) wproj1_t 36864 | 147456) wqkv2_t 110592 | 258048) wproj2_t 36864
__global__ void prep_weights(const float* __restrict__ qkv1, const float* __restrict__ proj1,
                             const float* __restrict__ qkv2, const float* __restrict__ proj2,
                             u16* __restrict__ ws)
{
    const int i = blockIdx.x*blockDim.x + threadIdx.x;
    if (i < 110592) {
        const int n = i / 192, k = i - n*192;
        ws[i]          = f2bf(qkv1[k*576 + n]);
        ws[147456 + i] = f2bf(qkv2[k*576 + n]);
    }
    if (i < 36864) {
        const int n = i / 192, k = i - n*192;
        ws[110592 + i] = f2bf(proj1[k*192 + n]);
        ws[258048 + i] = f2bf(proj2[k*192 + n]);
    }
}

extern "C" void kernel_launch(void* const* d_in, const int* in_sizes, int n_in,
                              void* d_out, int out_size, void* d_ws, size_t ws_size,
                              hipStream_t stream)
{
    const float* x       = (const float*)d_in[0];
    const float* ln1_g   = (const float*)d_in[1];
    const float* ln1_b   = (const float*)d_in[2];
    const float* qkv1_w  = (const float*)d_in[3];
    const float* qkv1_b  = (const float*)d_in[4];
    const float* proj1_w = (const float*)d_in[5];
    const float* proj1_b = (const float*)d_in[6];
    const float* ln2_g   = (const float*)d_in[7];
    const float* ln2_b   = (const float*)d_in[8];
    const float* qkv2_w  = (const float*)d_in[9];
    const float* qkv2_b  = (const float*)d_in[10];
    const float* proj2_w = (const float*)d_in[11];
    const float* proj2_b = (const float*)d_in[12];
    float* out = (float*)d_out;
    u16*   wsp = (u16*)d_ws;

    prep_weights<<<dim3(432), dim3(256), 0, stream>>>(qkv1_w, proj1_w, qkv2_w, proj2_w, wsp);
    // branch 1 (W-MSA): reads d_in x, writes d_out
    swin_branch<0><<<dim3(2048), dim3(384), 0, stream>>>(x,   out, ln1_g, ln1_b,
                                                         wsp,          qkv1_b, wsp+110592, proj1_b);
    // branch 2 (SW-MSA, shift=4): in-place on d_out (window pixels are WG-exclusive)
    swin_branch<4><<<dim3(2048), dim3(384), 0, stream>>>(out, out, ln2_g, ln2_b,
                                                         wsp+147456,   qkv2_b, wsp+258048, proj2_b);
}

// Round 2
// 349.636 us; speedup vs baseline: 1.2173x; 1.2173x over previous
//
#include <hip/hip_runtime.h>

typedef unsigned int   u32;
typedef unsigned short u16;
typedef __bf16 bf16x8 __attribute__((ext_vector_type(8)));
typedef float  f32x4  __attribute__((ext_vector_type(4)));

__device__ __forceinline__ u16 f2bf(float f) {
    u32 u = __builtin_bit_cast(u32, f);
    u += 0x7FFFu + ((u >> 16) & 1u);
    return (u16)(u >> 16);
}

__device__ __forceinline__ bf16x8 ldfrag(const u16* p) {
    return __builtin_bit_cast(bf16x8, *reinterpret_cast<const uint4*>(p));
}

// ---------------------------------------------------------------------------
// Fused Swin branch: LN -> QKV -> windowed MHA -> proj -> +residual
// One WG per 8x8 window; 384 threads = 6 waves = 6 heads.
// All LDS tensors stored in MFMA-fragment-major order [block][lane][8]:
// every ds_read_b128 / packed write is lane-contiguous => conflict-free.
// LDS budget ~75.5 KB => 2 WGs/CU (12 waves/CU).
//
// smem u16 layout:
//   Region A [0, 12288): yln as QKV-A frags: (mi*6+ks)*512 + lane*8 + j
//                        reused in phase 3 as V^T frags: h*2048 + (tv*2+ks)*512 + lane*8 + j
//   Region B [12288, 36864): per head h (4096 u16 @ B_OFF + h*4096):
//       q A-frags:   + mi*512 + lane*8 + j          (phase 2->3)
//       k B-frags:   + 2048 + ni*512 + lane*8 + j   (phase 2->3)
//       P A-frags:   + (mi*2+ks)*512 + lane*8 + j   (overlays q+k, phase 3)
//       attn_out:    + mi*512 + lane*8 + j          (overlays P, phase 3->4; per-head
//                                                    cols => proj-A frag block ks=h)
// ---------------------------------------------------------------------------
template<int SHIFT>
__global__ __launch_bounds__(384) void swin_branch(
    const float* __restrict__ xin, float* __restrict__ xout,
    const float* __restrict__ ln_g, const float* __restrict__ ln_b,
    const u16*   __restrict__ wqkv_t,  // [576][192] bf16 (pre-transposed)
    const float* __restrict__ qkv_b,   // [576]
    const u16*   __restrict__ wproj_t, // [192][192] bf16 (pre-transposed)
    const float* __restrict__ proj_b)  // [192]
{
    __shared__ __align__(16) u16 smem[36864];
    __shared__ float red1[6][64];
    __shared__ float red2[6][64];
    __shared__ float mu_s[64], rs_s[64];
    constexpr int B_OFF = 12288;

    const int tid  = threadIdx.x;
    const int wid  = tid >> 6;      // wave == head
    const int lane = tid & 63;
    const int lr   = lane & 15;
    const int lg   = lane >> 4;

    const int Wid = blockIdx.x;     // b*256 + wy*16 + wx
    const int b   = Wid >> 8;
    const int wy  = (Wid >> 4) & 15;
    const int wx  = Wid & 15;

    // ---- Phase 1: gather window (rolled), LayerNorm -> yln (A-frag layout) ----
    {
        const int ty = lane >> 3, tx = lane & 7;
        const int shy = (wy*8 + ty + SHIFT) & 127;
        const int shx = (wx*8 + tx + SHIFT) & 127;
        const float* xp = xin + ((size_t)((b*128 + shy)*128 + shx))*192 + wid*32;
        float xv[32];
        float s1 = 0.f, s2 = 0.f;
        #pragma unroll
        for (int j = 0; j < 8; ++j) {
            float4 v = reinterpret_cast<const float4*>(xp)[j];
            xv[j*4+0]=v.x; xv[j*4+1]=v.y; xv[j*4+2]=v.z; xv[j*4+3]=v.w;
            s1 += v.x+v.y+v.z+v.w;
            s2 += v.x*v.x + v.y*v.y + v.z*v.z + v.w*v.w;
        }
        red1[wid][lane] = s1; red2[wid][lane] = s2;
        __syncthreads();
        if (tid < 64) {
            float a1 = 0.f, a2 = 0.f;
            #pragma unroll
            for (int w = 0; w < 6; ++w) { a1 += red1[w][tid]; a2 += red2[w][tid]; }
            float mu  = a1 * (1.f/192.f);
            float var = a2 * (1.f/192.f) - mu*mu;
            mu_s[tid] = mu;
            rs_s[tid] = rsqrtf(var + 1e-5f);
        }
        __syncthreads();
        const float mu = mu_s[lane], rs = rs_s[lane];
        const float* gp = ln_g + wid*32;
        const float* bp = ln_b + wid*32;
        // element (token=lane, col=wid*32+cc) -> block((token>>4)*6+wid), lane'=(token&15)+16*(cc>>3), j=cc&7
        const u32 ybase = (u32)(((lane>>4)*6 + wid)*512 + (lane&15)*8);
        #pragma unroll
        for (int cc8 = 0; cc8 < 4; ++cc8) {
            u32 pk[4];
            #pragma unroll
            for (int q = 0; q < 4; ++q) {
                int j = cc8*8 + q*2;
                float y0 = (xv[j]   - mu)*rs*gp[j]   + bp[j];
                float y1 = (xv[j+1] - mu)*rs*gp[j+1] + bp[j+1];
                pk[q] = (u32)f2bf(y0) | ((u32)f2bf(y1) << 16);
            }
            *reinterpret_cast<uint4*>(&smem[ybase + cc8*128]) = make_uint4(pk[0],pk[1],pk[2],pk[3]);
        }
    }
    __syncthreads();

    // ---- Phase 2: QKV GEMM; wave h computes q_h | k_h | v_h (96 cols) ----
    f32x4 vacc[4][2];   // v stays in registers across the barrier
    {
        int colbase[6];
        #pragma unroll
        for (int t = 0; t < 6; ++t)
            colbase[t] = (t>>1)*192 + wid*32 + (t&1)*16;   // q,q,k,k,v,v 16-col tiles

        f32x4 acc[4][6];
        #pragma unroll
        for (int mi=0; mi<4; ++mi)
            #pragma unroll
            for (int t=0; t<6; ++t) acc[mi][t] = f32x4{0.f,0.f,0.f,0.f};
        #pragma unroll
        for (int ks=0; ks<6; ++ks) {
            bf16x8 af[4];
            #pragma unroll
            for (int mi=0; mi<4; ++mi)
                af[mi] = ldfrag(&smem[(mi*6+ks)*512 + lane*8]);
            bf16x8 bw[6];
            #pragma unroll
            for (int t=0; t<6; ++t)
                bw[t] = ldfrag(&wqkv_t[(colbase[t] + lr)*192 + 32*ks + 8*lg]);
            #pragma unroll
            for (int mi=0; mi<4; ++mi)
                #pragma unroll
                for (int t=0; t<6; ++t)
                    acc[mi][t] = __builtin_amdgcn_mfma_f32_16x16x32_bf16(af[mi], bw[t], acc[mi][t], 0,0,0);
        }
        // q (scaled) and k scatter into fragment-major LDS (conflict-free 2B stores)
        #pragma unroll
        for (int t=0; t<4; ++t) {
            const float bias = qkv_b[colbase[t] + lr];
            const bool  isq  = (t < 2);
            const int   tt   = t & 1;
            const u32 base2 = (u32)(B_OFF + wid*4096 + (isq ? 0 : 2048));
            const u32 lphi  = (u32)((2*tt + (lr>>3))*16);
            #pragma unroll
            for (int mi=0; mi<4; ++mi)
                #pragma unroll
                for (int rg=0; rg<4; ++rg) {
                    float v = acc[mi][t][rg] + bias;
                    if (isq) v *= 0.1767766952966369f;     // 1/sqrt(32)
                    const u32 lp = (u32)(4*lg + rg) + lphi;
                    smem[base2 + mi*512 + lp*8 + (lr&7)] = f2bf(v);
                }
        }
        #pragma unroll
        for (int tv=0; tv<2; ++tv) {
            const float bias = qkv_b[colbase[4+tv] + lr];
            #pragma unroll
            for (int mi=0; mi<4; ++mi) {
                vacc[mi][tv] = acc[mi][4+tv];
                #pragma unroll
                for (int rg=0; rg<4; ++rg) vacc[mi][tv][rg] += bias;
            }
        }
    }
    __syncthreads();   // all yln reads done -> region A reusable; q/k visible (wave-local anyway)

    // ---- Phase 3: attention, fully wave-local ----
    float rsum[4][4];
    f32x4 o_[4][2];
    {
        // V^T scatter into region A (own head's 2048-u16 block)
        const u32 vb = (u32)(wid*2048);
        #pragma unroll
        for (int tv=0; tv<2; ++tv)
            #pragma unroll
            for (int mi=0; mi<4; ++mi)
                #pragma unroll
                for (int rg=0; rg<4; ++rg) {
                    const int tok4 = 4*lg + rg;               // token&15
                    const int ksv  = mi >> 1;
                    const u32 lp   = (u32)(lr + 16*(2*(mi&1) + (tok4>>3)));
                    smem[vb + (tv*2+ksv)*512 + lp*8 + (tok4&7)] = f2bf(vacc[mi][tv][rg]);
                }
        __builtin_amdgcn_sched_barrier(0);   // pin v-writes before v-reads (no SSA dep)

        const u32 qb = (u32)(B_OFF + wid*4096);
        bf16x8 aq[4], bk[4];
        #pragma unroll
        for (int mi=0; mi<4; ++mi) aq[mi] = ldfrag(&smem[qb + mi*512 + lane*8]);
        #pragma unroll
        for (int ni=0; ni<4; ++ni) bk[ni] = ldfrag(&smem[qb + 2048 + ni*512 + lane*8]);

        f32x4 s[4][4];
        #pragma unroll
        for (int mi=0; mi<4; ++mi)
            #pragma unroll
            for (int ni=0; ni<4; ++ni)
                s[mi][ni] = __builtin_amdgcn_mfma_f32_16x16x32_bf16(aq[mi], bk[ni],
                                f32x4{0.f,0.f,0.f,0.f}, 0,0,0);

        if constexpr (SHIFT > 0) {
            int kl[4];
            #pragma unroll
            for (int ni=0; ni<4; ++ni) {
                const int col = 16*ni + lr;
                const int hu = wy*8 + (col>>3);
                const int wu = wx*8 + (col&7);
                kl[ni] = ((hu >= 124) ? 2 : (hu >= 120 ? 1 : 0))*3
                       + ((wu >= 124) ? 2 : (wu >= 120 ? 1 : 0));
            }
            #pragma unroll
            for (int mi=0; mi<4; ++mi)
                #pragma unroll
                for (int rg=0; rg<4; ++rg) {
                    const int row = 16*mi + 4*lg + rg;
                    const int hu = wy*8 + (row>>3);
                    const int wu = wx*8 + (row&7);
                    const int rl = ((hu >= 124) ? 2 : (hu >= 120 ? 1 : 0))*3
                                 + ((wu >= 124) ? 2 : (wu >= 120 ? 1 : 0));
                    #pragma unroll
                    for (int ni=0; ni<4; ++ni)
                        if (rl != kl[ni]) s[mi][ni][rg] += -100.f;
                }
        }

        // row softmax in registers (row's 64 cols = 16 lanes x 4 ni)
        #pragma unroll
        for (int mi=0; mi<4; ++mi)
            #pragma unroll
            for (int rg=0; rg<4; ++rg) {
                float m = fmaxf(fmaxf(s[mi][0][rg], s[mi][1][rg]), fmaxf(s[mi][2][rg], s[mi][3][rg]));
                #pragma unroll
                for (int off=1; off<16; off<<=1) m = fmaxf(m, __shfl_xor(m, off, 64));
                float sm = 0.f;
                #pragma unroll
                for (int ni=0; ni<4; ++ni) {
                    float e = __expf(s[mi][ni][rg] - m);
                    s[mi][ni][rg] = e;
                    sm += e;
                }
                #pragma unroll
                for (int off=1; off<16; off<<=1) sm += __shfl_xor(sm, off, 64);
                rsum[mi][rg] = 1.0f / sm;
            }

        // unnormalized P -> PV-A frags (overlays q+k, wave-local)
        #pragma unroll
        for (int mi=0; mi<4; ++mi)
            #pragma unroll
            for (int ni=0; ni<4; ++ni) {
                const u32 blk = qb + (u32)((mi*2 + (ni>>1))*512);
                const u32 lphi = (u32)(16*(2*(ni&1) + (lr>>3)));
                #pragma unroll
                for (int rg=0; rg<4; ++rg) {
                    const u32 lp = (u32)(4*lg + rg) + lphi;
                    smem[blk + lp*8 + (lr&7)] = f2bf(s[mi][ni][rg]);
                }
            }
        __builtin_amdgcn_sched_barrier(0);   // pin P-writes before P-reads

        #pragma unroll
        for (int mi=0; mi<4; ++mi)
            #pragma unroll
            for (int tv=0; tv<2; ++tv) o_[mi][tv] = f32x4{0.f,0.f,0.f,0.f};
        #pragma unroll
        for (int ksv=0; ksv<2; ++ksv) {
            bf16x8 ap[4], bv[2];
            #pragma unroll
            for (int mi=0; mi<4; ++mi) ap[mi] = ldfrag(&smem[qb + (mi*2+ksv)*512 + lane*8]);
            #pragma unroll
            for (int tv=0; tv<2; ++tv) bv[tv] = ldfrag(&smem[vb + (tv*2+ksv)*512 + lane*8]);
            #pragma unroll
            for (int mi=0; mi<4; ++mi)
                #pragma unroll
                for (int tv=0; tv<2; ++tv)
                    o_[mi][tv] = __builtin_amdgcn_mfma_f32_16x16x32_bf16(ap[mi], bv[tv], o_[mi][tv], 0,0,0);
        }
        // normalized attn_out -> proj-A frags (head block = own 4KB, overlays P)
        #pragma unroll
        for (int mi=0; mi<4; ++mi)
            #pragma unroll
            for (int tv=0; tv<2; ++tv) {
                const u32 lphi = (u32)(16*(2*tv + (lr>>3)));
                #pragma unroll
                for (int rg=0; rg<4; ++rg) {
                    const u32 lp = (u32)(4*lg + rg) + lphi;
                    smem[qb + mi*512 + lp*8 + (lr&7)] = f2bf(o_[mi][tv][rg] * rsum[mi][rg]);
                }
            }
    }
    __syncthreads();

    // ---- Phase 4: proj GEMM [64x192]@[192x192] + bias + residual ----
    {
        f32x4 a2[4][2];
        #pragma unroll
        for (int mi=0; mi<4; ++mi)
            #pragma unroll
            for (int ni=0; ni<2; ++ni) a2[mi][ni] = f32x4{0.f,0.f,0.f,0.f};
        #pragma unroll
        for (int ks=0; ks<6; ++ks) {
            bf16x8 af[4], bw[2];
            #pragma unroll
            for (int mi=0; mi<4; ++mi)
                af[mi] = ldfrag(&smem[B_OFF + ks*4096 + mi*512 + lane*8]);
            #pragma unroll
            for (int ni=0; ni<2; ++ni)
                bw[ni] = ldfrag(&wproj_t[(wid*32 + 16*ni + lr)*192 + 32*ks + 8*lg]);
            #pragma unroll
            for (int mi=0; mi<4; ++mi)
                #pragma unroll
                for (int ni=0; ni<2; ++ni)
                    a2[mi][ni] = __builtin_amdgcn_mfma_f32_16x16x32_bf16(af[mi], bw[ni], a2[mi][ni], 0,0,0);
        }
        #pragma unroll
        for (int ni=0; ni<2; ++ni) {
            const int c  = wid*32 + 16*ni + lr;
            const float pb = proj_b[c];
            #pragma unroll
            for (int mi=0; mi<4; ++mi)
                #pragma unroll
                for (int rg=0; rg<4; ++rg) {
                    const int row = 16*mi + 4*lg + rg;
                    const int ty = row >> 3, tx = row & 7;
                    const int shy = (wy*8 + ty + SHIFT) & 127;
                    const int shx = (wx*8 + tx + SHIFT) & 127;
                    const size_t idx = ((size_t)((b*128 + shy)*128 + shx))*192 + c;
                    xout[idx] = xin[idx] + a2[mi][ni][rg] + pb;
                }
        }
    }
}

// ws layout (u16): [0) wqkv1_t 110592 | 110592) wproj1_t 36864 | 147456) wqkv2_t 110592 | 258048) wproj2_t 36864
__global__ void prep_weights(const float* __restrict__ qkv1, const float* __restrict__ proj1,
                             const float* __restrict__ qkv2, const float* __restrict__ proj2,
                             u16* __restrict__ ws)
{
    const int i = blockIdx.x*blockDim.x + threadIdx.x;
    if (i < 110592) {
        const int n = i / 192, k = i - n*192;
        ws[i]          = f2bf(qkv1[k*576 + n]);
        ws[147456 + i] = f2bf(qkv2[k*576 + n]);
    }
    if (i < 36864) {
        const int n = i / 192, k = i - n*192;
        ws[110592 + i] = f2bf(proj1[k*192 + n]);
        ws[258048 + i] = f2bf(proj2[k*192 + n]);
    }
}

extern "C" void kernel_launch(void* const* d_in, const int* in_sizes, int n_in,
                              void* d_out, int out_size, void* d_ws, size_t ws_size,
                              hipStream_t stream)
{
    const float* x       = (const float*)d_in[0];
    const float* ln1_g   = (const float*)d_in[1];
    const float* ln1_b   = (const float*)d_in[2];
    const float* qkv1_w  = (const float*)d_in[3];
    const float* qkv1_b  = (const float*)d_in[4];
    const float* proj1_w = (const float*)d_in[5];
    const float* proj1_b = (const float*)d_in[6];
    const float* ln2_g   = (const float*)d_in[7];
    const float* ln2_b   = (const float*)d_in[8];
    const float* qkv2_w  = (const float*)d_in[9];
    const float* qkv2_b  = (const float*)d_in[10];
    const float* proj2_w = (const float*)d_in[11];
    const float* proj2_b = (const float*)d_in[12];
    float* out = (float*)d_out;
    u16*   wsp = (u16*)d_ws;

    prep_weights<<<dim3(432), dim3(256), 0, stream>>>(qkv1_w, proj1_w, qkv2_w, proj2_w, wsp);
    swin_branch<0><<<dim3(2048), dim3(384), 0, stream>>>(x,   out, ln1_g, ln1_b,
                                                         wsp,        qkv1_b, wsp+110592, proj1_b);
    swin_branch<4><<<dim3(2048), dim3(384), 0, stream>>>(out, out, ln2_g, ln2_b,
                                                         wsp+147456, qkv2_b, wsp+258048, proj2_b);
}